// Round 5
// baseline (426.480 us; speedup 1.0000x reference)
//
#include <hip/hip_runtime.h>
#include <hip/hip_cooperative_groups.h>

namespace cg = cooperative_groups;

// Output tile 64x64 per tile-job, input tile 36x36 (32 + 4 halo, 4-tap bicubic).
constexpr int IT  = 36;
constexpr int ITP = 37;   // sIn row stride (+1 pad)
constexpr int STP = 68;   // sT row stride: 16B-aligned, non-pow2 bank stride

// Bicubic (a = -0.75) x2-upsample phase weights, src = 0.5*i - 0.25.
#define W0 (-0.03515625f)
#define W1 ( 0.26171875f)
#define W2 ( 0.87890625f)
#define W3 (-0.10546875f)

// Native vector type: __builtin_nontemporal_store requires a real vector.
typedef float vfloat4 __attribute__((ext_vector_type(4)));

constexpr int NBLK  = 1024;   // cooperative grid: 4 blocks/CU co-resident
constexpr int TILES = 4096;   // 8 x 8 x 64 tiles total

// ---------------------------------------------------------------------------
// Tile pipeline: clamped 36x36 load -> horizontal upsample (36x64) ->
// vertical upsample; consume(it, v) gets 4x float4 per thread.
// Thread map: g = t&15 owns cols 4g..4g+3; rs = t>>4 owns rows rs+16k.
// Safe to call back-to-back: the two internal syncs also separate
// cross-iteration sIn/sT hazards (stage(i+1) vs hpass(i) ordered by sync2(i);
// hpass(i+1) vs vpass(i) ordered by sync1(i+1)).
// ---------------------------------------------------------------------------
template <typename F>
__device__ __forceinline__ void tile_pipeline(
    const float* __restrict__ src, int tx, int ty, int t,
    float (&sIn)[IT][ITP], float (&sT)[IT][STP],
    float a0, float a1, float a2, float a3, int b0, int g, F&& consume)
{
    const int rin0 = ty * 32 - 2;
    const int cin0 = tx * 32 - 2;

    for (int idx = t; idx < IT * IT; idx += 256) {
        int r  = idx / IT;
        int cc = idx - r * IT;
        int gr = min(max(rin0 + r, 0), 255);
        int gc = min(max(cin0 + cc, 0), 255);
        sIn[r][cc] = src[gr * 256 + gc];
    }
    __syncthreads();

    for (int r = t >> 4; r < IT; r += 16) {
        float x0 = sIn[r][2 * g + 0];
        float x1 = sIn[r][2 * g + 1];
        float x2 = sIn[r][2 * g + 2];
        float x3 = sIn[r][2 * g + 3];
        float x4 = sIn[r][2 * g + 4];
        float x5 = sIn[r][2 * g + 5];
        vfloat4 v;
        v.x = W0 * x0 + W1 * x1 + W2 * x2 + W3 * x3;
        v.y = W3 * x1 + W2 * x2 + W1 * x3 + W0 * x4;
        v.z = W0 * x1 + W1 * x2 + W2 * x3 + W3 * x4;
        v.w = W3 * x2 + W2 * x3 + W1 * x4 + W0 * x5;
        *(vfloat4*)&sT[r][4 * g] = v;
    }
    __syncthreads();

#pragma unroll
    for (int it = 0; it < 4; ++it) {
        const int base = b0 + 8 * it;
        vfloat4 q0 = *(const vfloat4*)&sT[base + 0][4 * g];
        vfloat4 q1 = *(const vfloat4*)&sT[base + 1][4 * g];
        vfloat4 q2 = *(const vfloat4*)&sT[base + 2][4 * g];
        vfloat4 q3 = *(const vfloat4*)&sT[base + 3][4 * g];
        vfloat4 v = a0 * q0 + a1 * q1 + a2 * q2 + a3 * q3;
        consume(it, v);
    }
}

// Block-wide min/max; on return ALL threads hold the block result.
// (Function-scope __shared__: one instance per block, reused across calls —
// calls here are separated by grid.sync(), so no WAR hazard.)
__device__ __forceinline__ void block_minmax(int t, float& mn, float& mx) {
    for (int off = 32; off > 0; off >>= 1) {
        mn = fminf(mn, __shfl_down(mn, off, 64));
        mx = fmaxf(mx, __shfl_down(mx, off, 64));
    }
    __shared__ float wmn[4], wmx[4];
    const int wv = t >> 6;
    if ((t & 63) == 0) { wmn[wv] = mn; wmx[wv] = mx; }
    __syncthreads();
    mn = fminf(fminf(wmn[0], wmn[1]), fminf(wmn[2], wmn[3]));
    mx = fmaxf(fmaxf(wmx[0], wmx[1]), fmaxf(wmx[2], wmx[3]));
}

// One cooperative launch replaces the 3-dispatch chain:
//   phase 1: 4 tiles/block -> unnormalized out + block min/max partial
//   grid.sync()
//   phase 2: every block reduces the 1024 partials (8KB, L2-hot), then
//            normalizes its own 4 tiles in place (same-XCD L2/L3-hot reads,
//            nontemporal final stores).
__global__ __launch_bounds__(256)
void qwt_fused(const float* __restrict__ LL, float* __restrict__ out,
               float* __restrict__ pmin, float* __restrict__ pmax)
{
    __shared__ float sIn[IT][ITP];
    __shared__ float sT[IT][STP];

    const int t = threadIdx.x;
    const int b = blockIdx.x;

    const int g  = t & 15;
    const int rs = t >> 4;
    const int od = rs & 1;
    const int b0 = (rs >> 1) + od;
    const float a0 = od ? W3 : W0;
    const float a1 = od ? W2 : W1;
    const float a2 = od ? W1 : W2;
    const float a3 = od ? W0 : W3;

    float mn = 1e30f, mx = -1e30f;

#pragma unroll
    for (int i = 0; i < TILES / NBLK; ++i) {
        const int tau = b + NBLK * i;
        const int tx = tau & 7;
        const int ty = (tau >> 3) & 7;
        const int pl = tau >> 6;
        const float* src = LL + (size_t)((pl >> 3) * 32 + (pl & 7)) * (256 * 256);
        float* dst = out + (size_t)pl * (512 * 512)
                   + (size_t)(ty * 64 + rs) * 512 + tx * 64 + 4 * g;

        tile_pipeline(src, tx, ty, t, sIn, sT, a0, a1, a2, a3, b0, g,
            [&](int it, vfloat4 v) {
                mn = fminf(mn, fminf(fminf(v.x, v.y), fminf(v.z, v.w)));
                mx = fmaxf(mx, fmaxf(fmaxf(v.x, v.y), fmaxf(v.z, v.w)));
                *(vfloat4*)(dst + (size_t)(16 * it) * 512) = v;
            });
    }

    block_minmax(t, mn, mx);
    if (t == 0) { pmin[b] = mn; pmax[b] = mx; }

    cg::this_grid().sync();   // device-scope fence + barrier

    // Reduce the 1024 partials (every block redundantly; 8KB L2-hot).
    float m = 1e30f, M = -1e30f;
#pragma unroll
    for (int k = 0; k < NBLK / 256; ++k) {
        m = fminf(m, pmin[t + 256 * k]);
        M = fmaxf(M, pmax[t + 256 * k]);
    }
    block_minmax(t, m, M);
    const float sub = m;
    const float scl = 1.0f / (M - m);

    // Normalize own tiles in place (reads hit same-XCD L2 / L3).
#pragma unroll
    for (int i = 0; i < TILES / NBLK; ++i) {
        const int tau = b + NBLK * i;
        const int tx = tau & 7;
        const int ty = (tau >> 3) & 7;
        const int pl = tau >> 6;
        float* dst = out + (size_t)pl * (512 * 512)
                   + (size_t)(ty * 64 + rs) * 512 + tx * 64 + 4 * g;
#pragma unroll
        for (int it = 0; it < 4; ++it) {
            vfloat4 v = *(vfloat4*)(dst + (size_t)(16 * it) * 512);
            __builtin_nontemporal_store((v - sub) * scl,
                                        (vfloat4*)(dst + (size_t)(16 * it) * 512));
        }
    }
}

extern "C" void kernel_launch(void* const* d_in, const int* in_sizes, int n_in,
                              void* d_out, int out_size, void* d_ws, size_t ws_size,
                              hipStream_t stream)
{
    (void)in_sizes; (void)n_in; (void)out_size; (void)ws_size;
    const float* LL = (const float*)d_in[0];
    float* out      = (float*)d_out;

    // ws: [0,1024) per-block mins, [1024,2048) per-block maxs.
    // Every slot is written in phase 1 before any phase-2 read (grid.sync
    // orders them) — 0xAA poison is fine.
    float* pmin = (float*)d_ws;
    float* pmax = pmin + NBLK;

    void* args[] = { (void*)&LL, (void*)&out, (void*)&pmin, (void*)&pmax };
    hipLaunchCooperativeKernel((void*)qwt_fused, dim3(NBLK), dim3(256),
                               args, 0, stream);
}